// Round 3
// baseline (423.480 us; speedup 1.0000x reference)
//
#include <hip/hip_runtime.h>
#include <cstdint>
#include <cstddef>

// ---- problem constants (B=2, C=512, H=W=32, G=8, Cg=64, h2=w2=8) ----
#define BATCH 2
#define CCH   512
#define HWPIX 1024           // 32*32
#define NBG   16             // B*G
#define JPIX  64             // 8*8
#define SCALE 0.125f         // 64^-0.5

typedef short bh8 __attribute__((ext_vector_type(8)));   // 8 x bf16 (4 VGPRs)
typedef float f32x4 __attribute__((ext_vector_type(4)));
typedef unsigned short u16;

__device__ __forceinline__ u16 f2bf(float f){
  unsigned u = __float_as_uint(f);
  unsigned r = (u + 0x7FFFu + ((u>>16)&1u))>>16;   // RNE
  return (u16)r;
}
__device__ __forceinline__ float geluf(float v){ return 0.5f*v*(1.0f + erff(v*0.70710678118654752f)); }
__device__ __forceinline__ float rdlane(float v, int l){
  return __uint_as_float(__builtin_amdgcn_readlane(__float_as_uint(v), l));
}

// ---------------- BatchNorm (per-channel over B*HW) ----------------
__global__ __launch_bounds__(256) void bn_kernel(const float* __restrict__ src,
      const float* __restrict__ g, const float* __restrict__ bta, float* __restrict__ dst){
  int c = blockIdx.x; int t = threadIdx.x;
  float s=0.f, ss=0.f;
  for(int b=0;b<BATCH;b++){
    size_t base = (size_t)b*CCH*HWPIX + (size_t)c*HWPIX;
    for(int p=t;p<HWPIX;p+=256){
      float v = src[base+p];
      s += v; ss += v*v;
    }
  }
  for(int o=32;o;o>>=1){ s += __shfl_down(s,o); ss += __shfl_down(ss,o); }
  __shared__ float ls[4], lss[4];
  __shared__ float sc, sh;
  int w = t>>6, lane = t&63;
  if(lane==0){ ls[w]=s; lss[w]=ss; }
  __syncthreads();
  if(t==0){
    float S=ls[0]+ls[1]+ls[2]+ls[3], SS=lss[0]+lss[1]+lss[2]+lss[3];
    float m = S*(1.0f/2048.0f);
    float var = SS*(1.0f/2048.0f) - m*m;
    float r = rsqrtf(var + 1e-5f);
    sc = r*g[c]; sh = bta[c] - m*r*g[c];
  }
  __syncthreads();
  float A = sc, Bv = sh;
  for(int b=0;b<BATCH;b++){
    size_t base = (size_t)b*CCH*HWPIX + (size_t)c*HWPIX;
    for(int p=t;p<HWPIX;p+=256){
      dst[base+p] = src[base+p]*A + Bv;
    }
  }
}

// ------- generic bf16-MFMA GEMM: out[b][m][n] = W[m][k] @ X[b][k][n] (+bias/gelu/res) -------
// W,X are f32 in global; both tiles staged to LDS as bf16. Wave w owns N-subtile w*16..+15.
__global__ __launch_bounds__(256) void gemm_kernel(
    const float* __restrict__ W, const float* __restrict__ X,
    float* __restrict__ outF,
    const float* __restrict__ bias, const float* __restrict__ resF,
    int M, int K, int Nb, int wMask, int wStride, int doGelu){
  __shared__ __align__(16) u16 xT[64*72];           // [n][k] bf16, row stride 72 (16B-aligned)
  __shared__ __align__(16) u16 wT[64*72];           // [m][k] bf16
  int t = threadIdx.x;
  int n0 = blockIdx.x*64, m0 = blockIdx.y*64, batch = blockIdx.z;
  const float* Wg = W + (size_t)(batch & wMask)*wStride;
  size_t xBase = (size_t)batch*K*Nb;
  int w = t>>6, lane = t&63, l15 = lane&15, quad = lane>>4;
  f32x4 acc[4];
  #pragma unroll
  for(int mt=0;mt<4;mt++) acc[mt] = (f32x4){0.f,0.f,0.f,0.f};
  for(int kc=0;kc<K;kc+=64){
    #pragma unroll
    for(int r=0;r<16;r++){
      int idx = r*256 + t;
      int k = idx>>6, nn = idx&63;                  // X: consecutive nn -> coalesced
      xT[nn*72 + k] = f2bf(X[xBase + (size_t)(kc+k)*Nb + n0 + nn]);
      int k1 = idx&63, mm = idx>>6;                 // W: consecutive k1 -> coalesced
      wT[mm*72 + k1] = f2bf(Wg[(size_t)(m0+mm)*K + kc + k1]);
    }
    __syncthreads();
    #pragma unroll
    for(int ks=0;ks<2;ks++){
      bh8 bF = *(const bh8*)&xT[(w*16 + l15)*72 + ks*32 + quad*8];
      #pragma unroll
      for(int mt=0;mt<4;mt++){
        bh8 aF = *(const bh8*)&wT[(mt*16 + l15)*72 + ks*32 + quad*8];
        acc[mt] = __builtin_amdgcn_mfma_f32_16x16x32_bf16(aF, bF, acc[mt], 0,0,0);
      }
    }
    __syncthreads();
  }
  int n = n0 + w*16 + l15;
  size_t oB = (size_t)batch*M*Nb;
  #pragma unroll
  for(int mt=0;mt<4;mt++){
    #pragma unroll
    for(int reg=0;reg<4;reg++){
      int m = m0 + mt*16 + quad*4 + reg;        // C/D: col=lane&15, row=quad*4+reg
      float v = acc[mt][reg];
      if(bias) v += bias[m];
      if(doGelu) v = geluf(v);
      size_t a = oB + (size_t)m*Nb + n;
      if(resF) v += resF[a];
      outF[a] = v;
    }
  }
}

// ------------- depthwise 6x6 stride-4 pad-1 conv + exact gelu -------------
__global__ __launch_bounds__(256) void dwconv_kernel(const float* __restrict__ q,
    const float* __restrict__ dw, const float* __restrict__ dwb, float* __restrict__ offg){
  int t = threadIdx.x;
  int bgc = blockIdx.x*4 + (t>>6);       // 0..1023 = bg*64 + c
  int c = bgc & 63;
  int pix = t&63;
  int oy = pix>>3, ox = pix&7;
  const float* img = q + (size_t)bgc*HWPIX;
  float acc = dwb[c];
  #pragma unroll
  for(int ky=0;ky<6;ky++){
    int y = oy*4 - 1 + ky;
    if(y<0 || y>31) continue;
    #pragma unroll
    for(int kx=0;kx<6;kx++){
      int x = ox*4 - 1 + kx;
      if(x<0 || x>31) continue;
      acc = fmaf(img[y*32 + x], dw[c*36 + ky*6 + kx], acc);
    }
  }
  offg[(size_t)bgc*64 + pix] = geluf(acc);
}

// ------------- pointwise 64->2, tanh*4, build sampling grid -------------
__global__ __launch_bounds__(64) void pwgrid_kernel(const float* __restrict__ offg,
    const float* __restrict__ pw, float* __restrict__ vgrid){
  int bg = blockIdx.x; int p = threadIdx.x;
  float a0=0.f, a1=0.f;
  for(int c=0;c<64;c++){
    float v = offg[(size_t)bg*4096 + c*64 + p];
    a0 = fmaf(v, pw[c], a0);
    a1 = fmaf(v, pw[64+c], a1);
  }
  float o0 = tanhf(a0)*4.0f, o1 = tanhf(a1)*4.0f;
  float gx = (float)(p&7), gy = (float)(p>>3);
  float vxx = (2.0f/7.0f)*(gx + o0) - 1.0f;
  float vyy = (2.0f/7.0f)*(gy + o1) - 1.0f;
  vgrid[bg*128 + p*2]     = vxx;
  vgrid[bg*128 + p*2 + 1] = vyy;
}

// ------------- bilinear grid sample (zero padding) -------------
__device__ __forceinline__ float fetchpix(const float* img, int ix, int iy){
  return (ix>=0 && ix<32 && iy>=0 && iy<32) ? img[iy*32+ix] : 0.0f;
}
__global__ __launch_bounds__(256) void sample_kernel(const float* __restrict__ xn,
    const float* __restrict__ vgrid, float* __restrict__ kv){
  int bg = blockIdx.x; int t = threadIdx.x;
  int p = t&63, cblk = t>>6;
  float vx = vgrid[bg*128 + p*2], vy = vgrid[bg*128 + p*2+1];
  float xs = ((vx + 1.0f)*32.0f - 1.0f)*0.5f;
  float ys = ((vy + 1.0f)*32.0f - 1.0f)*0.5f;
  float x0 = floorf(xs), y0 = floorf(ys);
  float wx = xs - x0, wy = ys - y0;
  int ix0 = (int)x0, iy0 = (int)y0;
  int b = bg>>3, g = bg&7;
  float w00 = (1.f-wx)*(1.f-wy), w10 = wx*(1.f-wy), w01 = (1.f-wx)*wy, w11 = wx*wy;
  for(int cc=0;cc<16;cc++){
    int c = cblk*16 + cc;
    const float* img = xn + (size_t)b*CCH*HWPIX + (size_t)(g*64+c)*HWPIX;
    float acc = w00*fetchpix(img,ix0,iy0)   + w10*fetchpix(img,ix0+1,iy0)
              + w01*fetchpix(img,ix0,iy0+1) + w11*fetchpix(img,ix0+1,iy0+1);
    kv[(size_t)bg*4096 + c*64 + p] = acc;
  }
}

// ------------- CPB bias MLP: per (bg,j) block, 1024 i-rows, layer2 via MFMA -------------
__global__ __launch_bounds__(256) void biasmlp_kernel(
    const float* __restrict__ w0, const float* __restrict__ b0,
    const float* __restrict__ w1, const float* __restrict__ b1,
    const float* __restrict__ w2, const float* __restrict__ b2,
    const float* __restrict__ vgrid, float* __restrict__ biasOut){
  __shared__ __align__(16) u16 w1t[128*136];   // W1 transposed: [n][k] bf16
  __shared__ __align__(16) u16 h0[64*136];     // layer-1 output tile: [row][k] bf16
  int t = threadIdx.x;
  int bg = blockIdx.x >> 6, jj = blockIdx.x & 63;
  for(int e=t;e<16384;e+=256){
    int k = e>>7, n = e&127;
    w1t[n*136 + k] = f2bf(w1[e]);              // w1 is [k][n] row-major f32
  }
  float vx = vgrid[bg*128 + jj*2];
  float vy = vgrid[bg*128 + jj*2 + 1];
  int lane = t&63, w = t>>6, l15 = lane&15, quad = lane>>4;
  __syncthreads();
  bh8 bfr[8][4];                               // B-fragments: all 8 N-tiles x 4 K-steps
  float b1f[8], w2f[8];
  #pragma unroll
  for(int nt=0;nt<8;nt++){
    int n = nt*16 + l15;
    b1f[nt] = b1[n];
    w2f[nt] = w2[n];
    #pragma unroll
    for(int ks=0;ks<4;ks++)
      bfr[nt][ks] = *(const bh8*)&w1t[n*136 + ks*32 + quad*8];
  }
  float b2v = b2[0];
  int r = t>>2, cb = (t&3)*32;
  for(int s=0;s<16;s++){
    int i = s*64 + r;
    int gx = i&31, gy = i>>5;
    float px = (2.0f/31.0f)*(float)gx - 1.0f - vx;
    float py = (2.0f/31.0f)*(float)gy - 1.0f - vy;
    float u = copysignf(log1pf(fabsf(px)), px);
    float v = copysignf(log1pf(fabsf(py)), py);
    #pragma unroll
    for(int c=0;c<32;c++){
      int n = cb + c;
      float h = fmaf(u, w0[n], fmaf(v, w0[128+n], b0[n]));
      h0[r*136 + n] = f2bf(fmaxf(h, 0.0f));
    }
    __syncthreads();
    f32x4 acc[8];
    #pragma unroll
    for(int nt=0;nt<8;nt++) acc[nt]=(f32x4){0.f,0.f,0.f,0.f};
    #pragma unroll
    for(int ks=0;ks<4;ks++){
      bh8 aF = *(const bh8*)&h0[(w*16 + l15)*136 + ks*32 + quad*8];
      #pragma unroll
      for(int nt=0;nt<8;nt++)
        acc[nt] = __builtin_amdgcn_mfma_f32_16x16x32_bf16(aF, bfr[nt][ks], acc[nt],0,0,0);
    }
    #pragma unroll
    for(int reg=0;reg<4;reg++){
      float p = 0.f;
      #pragma unroll
      for(int nt=0;nt<8;nt++){
        float h1 = fmaxf(acc[nt][reg] + b1f[nt], 0.0f);
        p = fmaf(h1, w2f[nt], p);
      }
      p += __shfl_xor(p, 1);
      p += __shfl_xor(p, 2);
      p += __shfl_xor(p, 4);
      p += __shfl_xor(p, 8);
      if(l15==0){
        int irow = s*64 + w*16 + quad*4 + reg;
        biasOut[(size_t)bg*65536 + (size_t)irow*64 + jj] = p + b2v;
      }
    }
    __syncthreads();
  }
}

// ------------- attention: per (bg, i-row): softmax(q·K*scale + bias) @ V -------------
__global__ __launch_bounds__(256) void attn_kernel(
    const float* __restrict__ qb, const float* __restrict__ kb, const float* __restrict__ vb,
    const float* __restrict__ biasb, float* __restrict__ ob){
  __shared__ float qT[64*65], kT[64*65], vT[64*65];
  int t = threadIdx.x;
  int bg = blockIdx.x>>4, itile = blockIdx.x&15;
  int i0 = itile*64;
  size_t qBase = (size_t)bg*65536;        // == b*C*HW + g*64*HW
  for(int e=t;e<4096;e+=256){
    int d = e>>6, x = e&63;
    qT[d*65 + x] = qb[qBase + (size_t)d*HWPIX + i0 + x];
    kT[d*65 + x] = kb[(size_t)bg*4096 + e];
    vT[d*65 + x] = vb[(size_t)bg*4096 + e];
  }
  __syncthreads();
  int lane = t&63, w = t>>6;
  for(int rr=0;rr<16;rr++){
    int il = w*16 + rr;
    int i = i0 + il;
    float qreg = qT[lane*65 + il];     // lane l holds q[i][d=l]
    float s0=0.f,s1=0.f,s2=0.f,s3=0.f;
    #pragma unroll 4
    for(int d=0;d<64;d+=4){
      s0 = fmaf(rdlane(qreg,d  ), kT[(d  )*65 + lane], s0);
      s1 = fmaf(rdlane(qreg,d+1), kT[(d+1)*65 + lane], s1);
      s2 = fmaf(rdlane(qreg,d+2), kT[(d+2)*65 + lane], s2);
      s3 = fmaf(rdlane(qreg,d+3), kT[(d+3)*65 + lane], s3);
    }
    float s = (s0+s1)+(s2+s3);
    s = s*SCALE + biasb[(size_t)bg*65536 + (size_t)i*64 + lane];
    float m = s;
    for(int msk=32;msk;msk>>=1) m = fmaxf(m, __shfl_xor(m, msk));
    float p = __expf(s - m);
    float l = p;
    for(int msk=32;msk;msk>>=1) l += __shfl_xor(l, msk);
    p = p / l;
    float o0=0.f,o1=0.f,o2=0.f,o3=0.f;
    #pragma unroll 4
    for(int j=0;j<64;j+=4){
      o0 = fmaf(rdlane(p,j  ), vT[lane*65 + j  ], o0);
      o1 = fmaf(rdlane(p,j+1), vT[lane*65 + j+1], o1);
      o2 = fmaf(rdlane(p,j+2), vT[lane*65 + j+2], o2);
      o3 = fmaf(rdlane(p,j+3), vT[lane*65 + j+3], o3);
    }
    ob[qBase + (size_t)lane*HWPIX + i] = (o0+o1)+(o2+o3);
  }
}

extern "C" void kernel_launch(void* const* d_in, const int* in_sizes, int n_in,
                              void* d_out, int out_size, void* d_ws, size_t ws_size,
                              hipStream_t stream){
  const float* x    = (const float*)d_in[0];
  const float* n1g  = (const float*)d_in[1];
  const float* n1b  = (const float*)d_in[2];
  const float* n2g  = (const float*)d_in[3];
  const float* n2b  = (const float*)d_in[4];
  const float* qw   = (const float*)d_in[5];
  const float* kw   = (const float*)d_in[6];
  const float* vw   = (const float*)d_in[7];
  const float* dww  = (const float*)d_in[8];
  const float* dwb  = (const float*)d_in[9];
  const float* pww  = (const float*)d_in[10];
  const float* cw0  = (const float*)d_in[11];
  const float* cb0  = (const float*)d_in[12];
  const float* cw1  = (const float*)d_in[13];
  const float* cb1  = (const float*)d_in[14];
  const float* cw2  = (const float*)d_in[15];
  const float* cb2  = (const float*)d_in[16];
  const float* ow   = (const float*)d_in[17];
  const float* obb  = (const float*)d_in[18];
  const float* m1w  = (const float*)d_in[19];
  const float* m1b  = (const float*)d_in[20];
  const float* m2w  = (const float*)d_in[21];
  const float* m2b  = (const float*)d_in[22];
  float* out = (float*)d_out;          // reference output dtype is float32
  float* ws = (float*)d_ws;

  // liveness-packed workspace (floats); total 6291456 floats = 25.2 MB
  float* xn      = ws;                 // 1M, live: bn1..sample, then reused by bn2..mlp1
  float* x2      = ws + 1048576;       // 1M, live: outproj..mlp2
  float* q       = ws + 2097152;       // 1M, dead after attn
  float* attnout = ws + 3145728;       // 1M, dead after outproj
  float* biasb   = ws + 4194304;       // 1M, dead after attn
  float* offg    = ws + 5242880;       // 64K
  float* kv      = ws + 5308416;       // 64K
  float* kbuf    = ws + 5373952;       // 64K
  float* vbuf    = ws + 5439488;       // 64K
  float* vgrid   = ws + 5505024;       // 2K
  float* h       = ws + 2097152;       // 4M, created at mlp1 over dead {q,attnout,biasb,smalls}

  bn_kernel<<<512,256,0,stream>>>(x, n1g, n1b, xn);
  // q = grouped conv1x1 (per-bg 64x64 @ 64x1024), W batch = g = bg&7
  gemm_kernel<<<dim3(16,1,16),256,0,stream>>>(qw, xn, q, nullptr, nullptr,
                                              64,64,1024, 7, 4096, 0);
  dwconv_kernel<<<256,256,0,stream>>>(q, dww, dwb, offg);
  pwgrid_kernel<<<16,64,0,stream>>>(offg, pww, vgrid);
  sample_kernel<<<16,256,0,stream>>>(xn, vgrid, kv);
  gemm_kernel<<<dim3(1,1,16),256,0,stream>>>(kw, kv, kbuf, nullptr, nullptr,
                                             64,64,64, 7, 4096, 0);
  gemm_kernel<<<dim3(1,1,16),256,0,stream>>>(vw, kv, vbuf, nullptr, nullptr,
                                             64,64,64, 7, 4096, 0);
  biasmlp_kernel<<<1024,256,0,stream>>>(cw0, cb0, cw1, cb1, cw2, cb2, vgrid, biasb);
  attn_kernel<<<256,256,0,stream>>>(q, kbuf, vbuf, biasb, attnout);
  // x2 = x + out_w @ attnout + out_b
  gemm_kernel<<<dim3(16,8,2),256,0,stream>>>(ow, attnout, x2, obb, x,
                                             512,512,1024, 0,0,0);
  bn_kernel<<<512,256,0,stream>>>(x2, n2g, n2b, xn);
  // h = gelu(mlp_w1 @ xn + b1)
  gemm_kernel<<<dim3(16,32,2),256,0,stream>>>(m1w, xn, h, m1b, nullptr,
                                              2048,512,1024, 0,0,1);
  // out = x2 + mlp_w2 @ h + b2  (f32 out)
  gemm_kernel<<<dim3(16,8,2),256,0,stream>>>(m2w, h, out, m2b, x2,
                                             512,2048,1024, 0,0,0);
}

// Round 4
// 357.081 us; speedup vs baseline: 1.1860x; 1.1860x over previous
//
#include <hip/hip_runtime.h>
#include <cstdint>
#include <cstddef>

// ---- problem constants (B=2, C=512, H=W=32, G=8, Cg=64, h2=w2=8) ----
#define BATCH 2
#define CCH   512
#define HWPIX 1024           // 32*32
#define NBG   16             // B*G
#define JPIX  64             // 8*8
#define SCALE 0.125f         // 64^-0.5

typedef short bh8 __attribute__((ext_vector_type(8)));   // 8 x bf16 (4 VGPRs)
typedef float f32x4 __attribute__((ext_vector_type(4)));
typedef unsigned short u16;

__device__ __forceinline__ u16 f2bf(float f){
  unsigned u = __float_as_uint(f);
  unsigned r = (u + 0x7FFFu + ((u>>16)&1u))>>16;   // RNE
  return (u16)r;
}
__device__ __forceinline__ float geluf(float v){ return 0.5f*v*(1.0f + erff(v*0.70710678118654752f)); }
__device__ __forceinline__ float rdlane(float v, int l){
  return __uint_as_float(__builtin_amdgcn_readlane(__float_as_uint(v), l));
}

// ---------------- BatchNorm (per-channel over B*HW) ----------------
__global__ __launch_bounds__(256) void bn_kernel(const float* __restrict__ src,
      const float* __restrict__ g, const float* __restrict__ bta, float* __restrict__ dst){
  int c = blockIdx.x; int t = threadIdx.x;
  float s=0.f, ss=0.f;
  for(int b=0;b<BATCH;b++){
    size_t base = (size_t)b*CCH*HWPIX + (size_t)c*HWPIX;
    for(int p=t;p<HWPIX;p+=256){
      float v = src[base+p];
      s += v; ss += v*v;
    }
  }
  for(int o=32;o;o>>=1){ s += __shfl_down(s,o); ss += __shfl_down(ss,o); }
  __shared__ float ls[4], lss[4];
  __shared__ float sc, sh;
  int w = t>>6, lane = t&63;
  if(lane==0){ ls[w]=s; lss[w]=ss; }
  __syncthreads();
  if(t==0){
    float S=ls[0]+ls[1]+ls[2]+ls[3], SS=lss[0]+lss[1]+lss[2]+lss[3];
    float m = S*(1.0f/2048.0f);
    float var = SS*(1.0f/2048.0f) - m*m;
    float r = rsqrtf(var + 1e-5f);
    sc = r*g[c]; sh = bta[c] - m*r*g[c];
  }
  __syncthreads();
  float A = sc, Bv = sh;
  for(int b=0;b<BATCH;b++){
    size_t base = (size_t)b*CCH*HWPIX + (size_t)c*HWPIX;
    for(int p=t;p<HWPIX;p+=256){
      dst[base+p] = src[base+p]*A + Bv;
    }
  }
}

// ------- generic bf16-MFMA GEMM: out[b][m][n] = W[m][k] @ X[b][k][n] (+bias/gelu/res) -------
// W,X are f32 in global; both tiles staged to LDS as bf16. Wave w owns N-subtile w*16..+15.
__global__ __launch_bounds__(256) void gemm_kernel(
    const float* __restrict__ W, const float* __restrict__ X,
    float* __restrict__ outF,
    const float* __restrict__ bias, const float* __restrict__ resF,
    int M, int K, int Nb, int wMask, int wStride, int doGelu){
  __shared__ __align__(16) u16 xT[64*72];           // [n][k] bf16, row stride 72 (16B-aligned)
  __shared__ __align__(16) u16 wT[64*72];           // [m][k] bf16
  int t = threadIdx.x;
  int n0 = blockIdx.x*64, m0 = blockIdx.y*64, batch = blockIdx.z;
  const float* Wg = W + (size_t)(batch & wMask)*wStride;
  size_t xBase = (size_t)batch*K*Nb;
  int w = t>>6, lane = t&63, l15 = lane&15, quad = lane>>4;
  f32x4 acc[4];
  #pragma unroll
  for(int mt=0;mt<4;mt++) acc[mt] = (f32x4){0.f,0.f,0.f,0.f};
  for(int kc=0;kc<K;kc+=64){
    #pragma unroll
    for(int r=0;r<16;r++){
      int idx = r*256 + t;
      int k = idx>>6, nn = idx&63;                  // X: consecutive nn -> coalesced
      xT[nn*72 + k] = f2bf(X[xBase + (size_t)(kc+k)*Nb + n0 + nn]);
      int k1 = idx&63, mm = idx>>6;                 // W: consecutive k1 -> coalesced
      wT[mm*72 + k1] = f2bf(Wg[(size_t)(m0+mm)*K + kc + k1]);
    }
    __syncthreads();
    #pragma unroll
    for(int ks=0;ks<2;ks++){
      bh8 bF = *(const bh8*)&xT[(w*16 + l15)*72 + ks*32 + quad*8];
      #pragma unroll
      for(int mt=0;mt<4;mt++){
        bh8 aF = *(const bh8*)&wT[(mt*16 + l15)*72 + ks*32 + quad*8];
        acc[mt] = __builtin_amdgcn_mfma_f32_16x16x32_bf16(aF, bF, acc[mt], 0,0,0);
      }
    }
    __syncthreads();
  }
  int n = n0 + w*16 + l15;
  size_t oB = (size_t)batch*M*Nb;
  #pragma unroll
  for(int mt=0;mt<4;mt++){
    #pragma unroll
    for(int reg=0;reg<4;reg++){
      int m = m0 + mt*16 + quad*4 + reg;        // C/D: col=lane&15, row=quad*4+reg
      float v = acc[mt][reg];
      if(bias) v += bias[m];
      if(doGelu) v = geluf(v);
      size_t a = oB + (size_t)m*Nb + n;
      if(resF) v += resF[a];
      outF[a] = v;
    }
  }
}

// ------------- depthwise 6x6 stride-4 pad-1 conv + exact gelu -------------
__global__ __launch_bounds__(256) void dwconv_kernel(const float* __restrict__ q,
    const float* __restrict__ dw, const float* __restrict__ dwb, float* __restrict__ offg){
  int t = threadIdx.x;
  int bgc = blockIdx.x*4 + (t>>6);       // 0..1023 = bg*64 + c
  int c = bgc & 63;
  int pix = t&63;
  int oy = pix>>3, ox = pix&7;
  const float* img = q + (size_t)bgc*HWPIX;
  float acc = dwb[c];
  #pragma unroll
  for(int ky=0;ky<6;ky++){
    int y = oy*4 - 1 + ky;
    if(y<0 || y>31) continue;
    #pragma unroll
    for(int kx=0;kx<6;kx++){
      int x = ox*4 - 1 + kx;
      if(x<0 || x>31) continue;
      acc = fmaf(img[y*32 + x], dw[c*36 + ky*6 + kx], acc);
    }
  }
  offg[(size_t)bgc*64 + pix] = geluf(acc);
}

// ------------- pointwise 64->2, tanh*4, build sampling grid -------------
__global__ __launch_bounds__(64) void pwgrid_kernel(const float* __restrict__ offg,
    const float* __restrict__ pw, float* __restrict__ vgrid){
  int bg = blockIdx.x; int p = threadIdx.x;
  float a0=0.f, a1=0.f;
  for(int c=0;c<64;c++){
    float v = offg[(size_t)bg*4096 + c*64 + p];
    a0 = fmaf(v, pw[c], a0);
    a1 = fmaf(v, pw[64+c], a1);
  }
  float o0 = tanhf(a0)*4.0f, o1 = tanhf(a1)*4.0f;
  float gx = (float)(p&7), gy = (float)(p>>3);
  float vxx = (2.0f/7.0f)*(gx + o0) - 1.0f;
  float vyy = (2.0f/7.0f)*(gy + o1) - 1.0f;
  vgrid[bg*128 + p*2]     = vxx;
  vgrid[bg*128 + p*2 + 1] = vyy;
}

// ------------- bilinear grid sample (zero padding) -------------
__device__ __forceinline__ float fetchpix(const float* img, int ix, int iy){
  return (ix>=0 && ix<32 && iy>=0 && iy<32) ? img[iy*32+ix] : 0.0f;
}
__global__ __launch_bounds__(256) void sample_kernel(const float* __restrict__ xn,
    const float* __restrict__ vgrid, float* __restrict__ kv){
  int bg = blockIdx.x; int t = threadIdx.x;
  int p = t&63, cblk = t>>6;
  float vx = vgrid[bg*128 + p*2], vy = vgrid[bg*128 + p*2+1];
  float xs = ((vx + 1.0f)*32.0f - 1.0f)*0.5f;
  float ys = ((vy + 1.0f)*32.0f - 1.0f)*0.5f;
  float x0 = floorf(xs), y0 = floorf(ys);
  float wx = xs - x0, wy = ys - y0;
  int ix0 = (int)x0, iy0 = (int)y0;
  int b = bg>>3, g = bg&7;
  float w00 = (1.f-wx)*(1.f-wy), w10 = wx*(1.f-wy), w01 = (1.f-wx)*wy, w11 = wx*wy;
  for(int cc=0;cc<16;cc++){
    int c = cblk*16 + cc;
    const float* img = xn + (size_t)b*CCH*HWPIX + (size_t)(g*64+c)*HWPIX;
    float acc = w00*fetchpix(img,ix0,iy0)   + w10*fetchpix(img,ix0+1,iy0)
              + w01*fetchpix(img,ix0,iy0+1) + w11*fetchpix(img,ix0+1,iy0+1);
    kv[(size_t)bg*4096 + c*64 + p] = acc;
  }
}

// ------------- CPB bias MLP: fragment-direct layer-0, layer-1 MFMA, layer-2 shfl-dot -------------
// Output layout: biasOut[bg][j][i]  (transposed vs attention's i-major use; attn stages via LDS)
__global__ __launch_bounds__(256,1) void biasmlp_kernel(
    const float* __restrict__ w0, const float* __restrict__ b0,
    const float* __restrict__ w1, const float* __restrict__ b1,
    const float* __restrict__ w2, const float* __restrict__ b2,
    const float* __restrict__ vgrid, float* __restrict__ biasOut){
  __shared__ __align__(16) u16 w1t[128*136];   // W1 transposed: [n][k] bf16
  int t = threadIdx.x;
  int bg = blockIdx.x >> 6, jj = blockIdx.x & 63;
  for(int e=t;e<16384;e+=256){
    int k = e>>7, n = e&127;
    w1t[n*136 + k] = f2bf(w1[e]);              // w1 is [k][n] row-major f32
  }
  float vx = vgrid[bg*128 + jj*2];
  float vy = vgrid[bg*128 + jj*2 + 1];
  int lane = t&63, w = t>>6, l15 = lane&15, quad = lane>>4;
  // per-lane layer-0 weights at this lane's A-fragment k-positions (k = ks*32 + quad*8 + j)
  float w0x[4][8], w0y[4][8], b0r[4][8];
  #pragma unroll
  for(int ks=0;ks<4;ks++){
    #pragma unroll
    for(int j=0;j<8;j++){
      int k = ks*32 + quad*8 + j;
      w0x[ks][j] = w0[k];
      w0y[ks][j] = w0[128+k];
      b0r[ks][j] = b0[k];
    }
  }
  __syncthreads();
  bh8 bfr[8][4];                               // B-fragments: all 8 N-tiles x 4 K-steps
  float b1f[8], w2f[8];
  #pragma unroll
  for(int nt=0;nt<8;nt++){
    int n = nt*16 + l15;
    b1f[nt] = b1[n];
    w2f[nt] = w2[n];
    #pragma unroll
    for(int ks=0;ks<4;ks++)
      bfr[nt][ks] = *(const bh8*)&w1t[n*136 + ks*32 + quad*8];
  }
  float b2v = b2[0];
  float* outP = biasOut + (size_t)bg*65536 + (size_t)jj*1024;
  for(int s=0;s<16;s++){
    int i = s*64 + w*16 + l15;                 // this lane's row
    float px = (2.0f/31.0f)*(float)(i&31) - 1.0f - vx;
    float py = (2.0f/31.0f)*(float)(i>>5) - 1.0f - vy;
    float u = copysignf(log1pf(fabsf(px)), px);
    float v = copysignf(log1pf(fabsf(py)), py);
    // build A fragments in-register: h0 = relu(u*w0x + v*w0y + b0), bf16-truncate, perm-pack
    union { bh8 v8; unsigned d[4]; } ah[4];
    #pragma unroll
    for(int ks=0;ks<4;ks++){
      #pragma unroll
      for(int d=0;d<4;d++){
        float he = fmaxf(fmaf(u, w0x[ks][2*d],   fmaf(v, w0y[ks][2*d],   b0r[ks][2*d]  )), 0.0f);
        float ho = fmaxf(fmaf(u, w0x[ks][2*d+1], fmaf(v, w0y[ks][2*d+1], b0r[ks][2*d+1])), 0.0f);
        // dword = [bf16(ho) : bf16(he)]  (truncation; err ~2^-8 rel, fine at these scales)
        ah[ks].d[d] = __builtin_amdgcn_perm(__float_as_uint(ho), __float_as_uint(he), 0x07060302u);
      }
    }
    f32x4 acc[8];
    #pragma unroll
    for(int nt=0;nt<8;nt++)                    // init with b1 (saves epilogue add)
      acc[nt] = (f32x4){b1f[nt], b1f[nt], b1f[nt], b1f[nt]};
    #pragma unroll
    for(int ks=0;ks<4;ks++){
      #pragma unroll
      for(int nt=0;nt<8;nt++)
        acc[nt] = __builtin_amdgcn_mfma_f32_16x16x32_bf16(ah[ks].v8, bfr[nt][ks], acc[nt],0,0,0);
    }
    float pr[4];
    #pragma unroll
    for(int reg=0;reg<4;reg++){
      float p = 0.f;
      #pragma unroll
      for(int nt=0;nt<8;nt++)
        p = fmaf(fmaxf(acc[nt][reg], 0.0f), w2f[nt], p);
      p += __shfl_xor(p, 1);
      p += __shfl_xor(p, 2);
      p += __shfl_xor(p, 4);
      p += __shfl_xor(p, 8);
      pr[reg] = p + b2v;
    }
    if(l15==0){                                // 4 lanes/wave, each a float4 -> 64B contiguous
      *(f32x4*)&outP[s*64 + w*16 + quad*4] = (f32x4){pr[0], pr[1], pr[2], pr[3]};
    }
  }
}

// ------------- attention: per (bg, i-row): softmax(q·K*scale + bias) @ V -------------
// bias is [bg][j][i]; staged through LDS with transpose for per-lane j access.
__global__ __launch_bounds__(256) void attn_kernel(
    const float* __restrict__ qb, const float* __restrict__ kb, const float* __restrict__ vb,
    const float* __restrict__ biasb, float* __restrict__ ob){
  __shared__ float qT[64*65], kT[64*65], vT[64*65], bT[64*65];
  int t = threadIdx.x;
  int bg = blockIdx.x>>4, itile = blockIdx.x&15;
  int i0 = itile*64;
  size_t qBase = (size_t)bg*65536;        // == b*C*HW + g*64*HW
  for(int e=t;e<4096;e+=256){
    int d = e>>6, x = e&63;
    qT[d*65 + x] = qb[qBase + (size_t)d*HWPIX + i0 + x];
    kT[d*65 + x] = kb[(size_t)bg*4096 + e];
    vT[d*65 + x] = vb[(size_t)bg*4096 + e];
    bT[x*65 + d] = biasb[(size_t)bg*65536 + (size_t)d*1024 + i0 + x];  // d=j, x=il
  }
  __syncthreads();
  int lane = t&63, w = t>>6;
  for(int rr=0;rr<16;rr++){
    int il = w*16 + rr;
    int i = i0 + il;
    float qreg = qT[lane*65 + il];     // lane l holds q[i][d=l]
    float s0=0.f,s1=0.f,s2=0.f,s3=0.f;
    #pragma unroll 4
    for(int d=0;d<64;d+=4){
      s0 = fmaf(rdlane(qreg,d  ), kT[(d  )*65 + lane], s0);
      s1 = fmaf(rdlane(qreg,d+1), kT[(d+1)*65 + lane], s1);
      s2 = fmaf(rdlane(qreg,d+2), kT[(d+2)*65 + lane], s2);
      s3 = fmaf(rdlane(qreg,d+3), kT[(d+3)*65 + lane], s3);
    }
    float s = (s0+s1)+(s2+s3);
    s = s*SCALE + bT[il*65 + lane];
    float m = s;
    for(int msk=32;msk;msk>>=1) m = fmaxf(m, __shfl_xor(m, msk));
    float p = __expf(s - m);
    float l = p;
    for(int msk=32;msk;msk>>=1) l += __shfl_xor(l, msk);
    p = p / l;
    float o0=0.f,o1=0.f,o2=0.f,o3=0.f;
    #pragma unroll 4
    for(int j=0;j<64;j+=4){
      o0 = fmaf(rdlane(p,j  ), vT[lane*65 + j  ], o0);
      o1 = fmaf(rdlane(p,j+1), vT[lane*65 + j+1], o1);
      o2 = fmaf(rdlane(p,j+2), vT[lane*65 + j+2], o2);
      o3 = fmaf(rdlane(p,j+3), vT[lane*65 + j+3], o3);
    }
    ob[qBase + (size_t)lane*HWPIX + i] = (o0+o1)+(o2+o3);
  }
}

extern "C" void kernel_launch(void* const* d_in, const int* in_sizes, int n_in,
                              void* d_out, int out_size, void* d_ws, size_t ws_size,
                              hipStream_t stream){
  const float* x    = (const float*)d_in[0];
  const float* n1g  = (const float*)d_in[1];
  const float* n1b  = (const float*)d_in[2];
  const float* n2g  = (const float*)d_in[3];
  const float* n2b  = (const float*)d_in[4];
  const float* qw   = (const float*)d_in[5];
  const float* kw   = (const float*)d_in[6];
  const float* vw   = (const float*)d_in[7];
  const float* dww  = (const float*)d_in[8];
  const float* dwb  = (const float*)d_in[9];
  const float* pww  = (const float*)d_in[10];
  const float* cw0  = (const float*)d_in[11];
  const float* cb0  = (const float*)d_in[12];
  const float* cw1  = (const float*)d_in[13];
  const float* cb1  = (const float*)d_in[14];
  const float* cw2  = (const float*)d_in[15];
  const float* cb2  = (const float*)d_in[16];
  const float* ow   = (const float*)d_in[17];
  const float* obb  = (const float*)d_in[18];
  const float* m1w  = (const float*)d_in[19];
  const float* m1b  = (const float*)d_in[20];
  const float* m2w  = (const float*)d_in[21];
  const float* m2b  = (const float*)d_in[22];
  float* out = (float*)d_out;          // reference output dtype is float32
  float* ws = (float*)d_ws;

  // liveness-packed workspace (floats); total 6291456 floats = 25.2 MB
  float* xn      = ws;                 // 1M, live: bn1..sample, then reused by bn2..mlp1
  float* x2      = ws + 1048576;       // 1M, live: outproj..mlp2
  float* q       = ws + 2097152;       // 1M, dead after attn
  float* attnout = ws + 3145728;       // 1M, dead after outproj
  float* biasb   = ws + 4194304;       // 1M, dead after attn  ([bg][j][i] layout)
  float* offg    = ws + 5242880;       // 64K
  float* kv      = ws + 5308416;       // 64K
  float* kbuf    = ws + 5373952;       // 64K
  float* vbuf    = ws + 5439488;       // 64K
  float* vgrid   = ws + 5505024;       // 2K
  float* h       = ws + 2097152;       // 4M, created at mlp1 over dead {q,attnout,biasb,smalls}

  bn_kernel<<<512,256,0,stream>>>(x, n1g, n1b, xn);
  // q = grouped conv1x1 (per-bg 64x64 @ 64x1024), W batch = g = bg&7
  gemm_kernel<<<dim3(16,1,16),256,0,stream>>>(qw, xn, q, nullptr, nullptr,
                                              64,64,1024, 7, 4096, 0);
  dwconv_kernel<<<256,256,0,stream>>>(q, dww, dwb, offg);
  pwgrid_kernel<<<16,64,0,stream>>>(offg, pww, vgrid);
  sample_kernel<<<16,256,0,stream>>>(xn, vgrid, kv);
  gemm_kernel<<<dim3(1,1,16),256,0,stream>>>(kw, kv, kbuf, nullptr, nullptr,
                                             64,64,64, 7, 4096, 0);
  gemm_kernel<<<dim3(1,1,16),256,0,stream>>>(vw, kv, vbuf, nullptr, nullptr,
                                             64,64,64, 7, 4096, 0);
  biasmlp_kernel<<<1024,256,0,stream>>>(cw0, cb0, cw1, cb1, cw2, cb2, vgrid, biasb);
  attn_kernel<<<256,256,0,stream>>>(q, kbuf, vbuf, biasb, attnout);
  // x2 = x + out_w @ attnout + out_b
  gemm_kernel<<<dim3(16,8,2),256,0,stream>>>(ow, attnout, x2, obb, x,
                                             512,512,1024, 0,0,0);
  bn_kernel<<<512,256,0,stream>>>(x2, n2g, n2b, xn);
  // h = gelu(mlp_w1 @ xn + b1)
  gemm_kernel<<<dim3(16,32,2),256,0,stream>>>(m1w, xn, h, m1b, nullptr,
                                              2048,512,1024, 0,0,1);
  // out = x2 + mlp_w2 @ h + b2  (f32 out)
  gemm_kernel<<<dim3(16,8,2),256,0,stream>>>(m2w, h, out, m2b, x2,
                                             512,2048,1024, 0,0,0);
}

// Round 6
// 314.101 us; speedup vs baseline: 1.3482x; 1.1368x over previous
//
#include <hip/hip_runtime.h>
#include <cstdint>
#include <cstddef>

// ---- problem constants (B=2, C=512, H=W=32, G=8, Cg=64, h2=w2=8) ----
#define BATCH 2
#define CCH   512
#define HWPIX 1024           // 32*32
#define NBG   16             // B*G
#define JPIX  64             // 8*8
#define SCALE 0.125f         // 64^-0.5

typedef short bh8 __attribute__((ext_vector_type(8)));   // 8 x bf16 (4 VGPRs)
typedef _Float16 h8 __attribute__((ext_vector_type(8))); // 8 x fp16 (4 VGPRs)
typedef _Float16 h2 __attribute__((ext_vector_type(2))); // 2 x fp16 (1 VGPR)
typedef float f32x4 __attribute__((ext_vector_type(4)));
typedef unsigned short u16;

__device__ __forceinline__ u16 f2bf(float f){
  unsigned u = __float_as_uint(f);
  unsigned r = (u + 0x7FFFu + ((u>>16)&1u))>>16;   // RNE
  return (u16)r;
}
__device__ __forceinline__ float geluf(float v){ return 0.5f*v*(1.0f + erff(v*0.70710678118654752f)); }
__device__ __forceinline__ float rdlane(float v, int l){
  return __uint_as_float(__builtin_amdgcn_readlane(__float_as_uint(v), l));
}

// ---------------- BatchNorm (per-channel over B*HW) ----------------
__global__ __launch_bounds__(256) void bn_kernel(const float* __restrict__ src,
      const float* __restrict__ g, const float* __restrict__ bta, float* __restrict__ dst){
  int c = blockIdx.x; int t = threadIdx.x;
  float s=0.f, ss=0.f;
  for(int b=0;b<BATCH;b++){
    size_t base = (size_t)b*CCH*HWPIX + (size_t)c*HWPIX;
    for(int p=t;p<HWPIX;p+=256){
      float v = src[base+p];
      s += v; ss += v*v;
    }
  }
  for(int o=32;o;o>>=1){ s += __shfl_down(s,o); ss += __shfl_down(ss,o); }
  __shared__ float ls[4], lss[4];
  __shared__ float sc, sh;
  int w = t>>6, lane = t&63;
  if(lane==0){ ls[w]=s; lss[w]=ss; }
  __syncthreads();
  if(t==0){
    float S=ls[0]+ls[1]+ls[2]+ls[3], SS=lss[0]+lss[1]+lss[2]+lss[3];
    float m = S*(1.0f/2048.0f);
    float var = SS*(1.0f/2048.0f) - m*m;
    float r = rsqrtf(var + 1e-5f);
    sc = r*g[c]; sh = bta[c] - m*r*g[c];
  }
  __syncthreads();
  float A = sc, Bv = sh;
  for(int b=0;b<BATCH;b++){
    size_t base = (size_t)b*CCH*HWPIX + (size_t)c*HWPIX;
    for(int p=t;p<HWPIX;p+=256){
      dst[base+p] = src[base+p]*A + Bv;
    }
  }
}

// ------- generic bf16-MFMA GEMM: out[b][m][n] = W[m][k] @ X[b][k][n] (+bias/gelu/res) -------
// W,X are f32 in global; both tiles staged to LDS as bf16. Wave w owns N-subtile w*16..+15.
__global__ __launch_bounds__(256) void gemm_kernel(
    const float* __restrict__ W, const float* __restrict__ X,
    float* __restrict__ outF,
    const float* __restrict__ bias, const float* __restrict__ resF,
    int M, int K, int Nb, int wMask, int wStride, int doGelu){
  __shared__ __align__(16) u16 xT[64*72];           // [n][k] bf16, row stride 72 (16B-aligned)
  __shared__ __align__(16) u16 wT[64*72];           // [m][k] bf16
  int t = threadIdx.x;
  int n0 = blockIdx.x*64, m0 = blockIdx.y*64, batch = blockIdx.z;
  const float* Wg = W + (size_t)(batch & wMask)*wStride;
  size_t xBase = (size_t)batch*K*Nb;
  int w = t>>6, lane = t&63, l15 = lane&15, quad = lane>>4;
  f32x4 acc[4];
  #pragma unroll
  for(int mt=0;mt<4;mt++) acc[mt] = (f32x4){0.f,0.f,0.f,0.f};
  for(int kc=0;kc<K;kc+=64){
    #pragma unroll
    for(int r=0;r<16;r++){
      int idx = r*256 + t;
      int k = idx>>6, nn = idx&63;                  // X: consecutive nn -> coalesced
      xT[nn*72 + k] = f2bf(X[xBase + (size_t)(kc+k)*Nb + n0 + nn]);
      int k1 = idx&63, mm = idx>>6;                 // W: consecutive k1 -> coalesced
      wT[mm*72 + k1] = f2bf(Wg[(size_t)(m0+mm)*K + kc + k1]);
    }
    __syncthreads();
    #pragma unroll
    for(int ks=0;ks<2;ks++){
      bh8 bF = *(const bh8*)&xT[(w*16 + l15)*72 + ks*32 + quad*8];
      #pragma unroll
      for(int mt=0;mt<4;mt++){
        bh8 aF = *(const bh8*)&wT[(mt*16 + l15)*72 + ks*32 + quad*8];
        acc[mt] = __builtin_amdgcn_mfma_f32_16x16x32_bf16(aF, bF, acc[mt], 0,0,0);
      }
    }
    __syncthreads();
  }
  int n = n0 + w*16 + l15;
  size_t oB = (size_t)batch*M*Nb;
  #pragma unroll
  for(int mt=0;mt<4;mt++){
    #pragma unroll
    for(int reg=0;reg<4;reg++){
      int m = m0 + mt*16 + quad*4 + reg;        // C/D: col=lane&15, row=quad*4+reg
      float v = acc[mt][reg];
      if(bias) v += bias[m];
      if(doGelu) v = geluf(v);
      size_t a = oB + (size_t)m*Nb + n;
      if(resF) v += resF[a];
      outF[a] = v;
    }
  }
}

// ------------- depthwise 6x6 stride-4 pad-1 conv + exact gelu -------------
__global__ __launch_bounds__(256) void dwconv_kernel(const float* __restrict__ q,
    const float* __restrict__ dw, const float* __restrict__ dwb, float* __restrict__ offg){
  int t = threadIdx.x;
  int bgc = blockIdx.x*4 + (t>>6);       // 0..1023 = bg*64 + c
  int c = bgc & 63;
  int pix = t&63;
  int oy = pix>>3, ox = pix&7;
  const float* img = q + (size_t)bgc*HWPIX;
  float acc = dwb[c];
  #pragma unroll
  for(int ky=0;ky<6;ky++){
    int y = oy*4 - 1 + ky;
    if(y<0 || y>31) continue;
    #pragma unroll
    for(int kx=0;kx<6;kx++){
      int x = ox*4 - 1 + kx;
      if(x<0 || x>31) continue;
      acc = fmaf(img[y*32 + x], dw[c*36 + ky*6 + kx], acc);
    }
  }
  offg[(size_t)bgc*64 + pix] = geluf(acc);
}

// ------------- pointwise 64->2, tanh*4, build sampling grid -------------
__global__ __launch_bounds__(64) void pwgrid_kernel(const float* __restrict__ offg,
    const float* __restrict__ pw, float* __restrict__ vgrid){
  int bg = blockIdx.x; int p = threadIdx.x;
  float a0=0.f, a1=0.f;
  for(int c=0;c<64;c++){
    float v = offg[(size_t)bg*4096 + c*64 + p];
    a0 = fmaf(v, pw[c], a0);
    a1 = fmaf(v, pw[64+c], a1);
  }
  float o0 = tanhf(a0)*4.0f, o1 = tanhf(a1)*4.0f;
  float gx = (float)(p&7), gy = (float)(p>>3);
  float vxx = (2.0f/7.0f)*(gx + o0) - 1.0f;
  float vyy = (2.0f/7.0f)*(gy + o1) - 1.0f;
  vgrid[bg*128 + p*2]     = vxx;
  vgrid[bg*128 + p*2 + 1] = vyy;
}

// ------------- bilinear grid sample (zero padding) -------------
__device__ __forceinline__ float fetchpix(const float* img, int ix, int iy){
  return (ix>=0 && ix<32 && iy>=0 && iy<32) ? img[iy*32+ix] : 0.0f;
}
__global__ __launch_bounds__(256) void sample_kernel(const float* __restrict__ xn,
    const float* __restrict__ vgrid, float* __restrict__ kv){
  int bg = blockIdx.x; int t = threadIdx.x;
  int p = t&63, cblk = t>>6;
  float vx = vgrid[bg*128 + p*2], vy = vgrid[bg*128 + p*2+1];
  float xs = ((vx + 1.0f)*32.0f - 1.0f)*0.5f;
  float ys = ((vy + 1.0f)*32.0f - 1.0f)*0.5f;
  float x0 = floorf(xs), y0 = floorf(ys);
  float wx = xs - x0, wy = ys - y0;
  int ix0 = (int)x0, iy0 = (int)y0;
  int b = bg>>3, g = bg&7;
  float w00 = (1.f-wx)*(1.f-wy), w10 = wx*(1.f-wy), w01 = (1.f-wx)*wy, w11 = wx*wy;
  for(int cc=0;cc<16;cc++){
    int c = cblk*16 + cc;
    const float* img = xn + (size_t)b*CCH*HWPIX + (size_t)(g*64+c)*HWPIX;
    float acc = w00*fetchpix(img,ix0,iy0)   + w10*fetchpix(img,ix0+1,iy0)
              + w01*fetchpix(img,ix0,iy0+1) + w11*fetchpix(img,ix0+1,iy0+1);
    kv[(size_t)bg*4096 + c*64 + p] = acc;
  }
}

// ------------- CPB bias MLP v3: packed-f16 layer-0 (u-part hoisted), f16 MFMA layer-1 -------------
// Output layout: biasOut[bg][j][i]  (attn stages/transposes via LDS)
__global__ __launch_bounds__(256,2) void biasmlp_kernel(
    const float* __restrict__ w0, const float* __restrict__ b0,
    const float* __restrict__ w1, const float* __restrict__ b1,
    const float* __restrict__ w2, const float* __restrict__ b2,
    const float* __restrict__ vgrid, float* __restrict__ biasOut){
  __shared__ __align__(16) _Float16 w1h[128*136];   // W1 transposed: [n][k] f16
  int t = threadIdx.x;
  int bg = blockIdx.x >> 6, jj = blockIdx.x & 63;
  for(int e=t;e<16384;e+=256){
    int k = e>>7, n = e&127;
    w1h[n*136 + k] = (_Float16)w1[e];             // w1 is [k][n] row-major f32
  }
  float vx = vgrid[bg*128 + jj*2];
  float vy = vgrid[bg*128 + jj*2 + 1];
  int lane = t&63, w = t>>6, l15 = lane&15, quad = lane>>4;
  // u is constant across s for this lane: i&31 == (w*16+l15)&31
  int gxi = (w*16 + l15)&31;
  float px = (2.0f/31.0f)*(float)gxi - 1.0f - vx;
  float u = copysignf(__logf(1.0f + fabsf(px)), px);
  // prologue: t1 = u*w0x + b0  and  wyp = w0y, packed f16 at this lane's k-positions
  h2 t1p[16], wyp[16];
  #pragma unroll
  for(int ks=0;ks<4;ks++){
    #pragma unroll
    for(int d=0;d<4;d++){
      int k = ks*32 + quad*8 + 2*d;
      t1p[ks*4+d] = (h2){(_Float16)fmaf(u, w0[k], b0[k]), (_Float16)fmaf(u, w0[k+1], b0[k+1])};
      wyp[ks*4+d] = (h2){(_Float16)w0[128+k], (_Float16)w0[128+k+1]};
    }
  }
  __syncthreads();
  h8 bfr[8][4];                               // W1 B-fragments: all 8 N-tiles x 4 K-steps
  float b1f[8], w2f[8];
  #pragma unroll
  for(int nt=0;nt<8;nt++){
    int n = nt*16 + l15;
    b1f[nt] = b1[n];
    w2f[nt] = w2[n];
    #pragma unroll
    for(int ks=0;ks<4;ks++)
      bfr[nt][ks] = *(const h8*)&w1h[n*136 + ks*32 + quad*8];
  }
  float b2v = b2[0];
  const h2 z2 = (h2){(_Float16)0.f, (_Float16)0.f};
  float* outP = biasOut + (size_t)bg*65536 + (size_t)jj*1024;
  for(int s=0;s<16;s++){
    int gyi = (s*64 + w*16 + l15)>>5;
    float py = (2.0f/31.0f)*(float)gyi - 1.0f - vy;
    float v = copysignf(__logf(1.0f + fabsf(py)), py);
    _Float16 vh = (_Float16)v;
    h2 v2 = (h2){vh, vh};
    // A fragments: h0 = relu(t1 + v*wy) -> v_pk_fma_f16 + v_pk_max_f16 per pair
    union { h2 p[4]; h8 v8; } ah[4];
    #pragma unroll
    for(int ks=0;ks<4;ks++){
      #pragma unroll
      for(int d=0;d<4;d++)
        ah[ks].p[d] = __builtin_elementwise_max(v2*wyp[ks*4+d] + t1p[ks*4+d], z2);
    }
    f32x4 acc[8];
    #pragma unroll
    for(int nt=0;nt<8;nt++)                    // init with b1 (saves epilogue add)
      acc[nt] = (f32x4){b1f[nt], b1f[nt], b1f[nt], b1f[nt]};
    #pragma unroll
    for(int ks=0;ks<4;ks++){
      #pragma unroll
      for(int nt=0;nt<8;nt++)
        acc[nt] = __builtin_amdgcn_mfma_f32_16x16x32_f16(ah[ks].v8, bfr[nt][ks], acc[nt],0,0,0);
    }
    float pr[4];
    #pragma unroll
    for(int reg=0;reg<4;reg++){
      float p = 0.f;
      #pragma unroll
      for(int nt=0;nt<8;nt++)
        p = fmaf(fmaxf(acc[nt][reg], 0.0f), w2f[nt], p);
      p += __shfl_xor(p, 1);
      p += __shfl_xor(p, 2);
      p += __shfl_xor(p, 4);
      p += __shfl_xor(p, 8);
      pr[reg] = p + b2v;
    }
    if(l15==0){                                // 4 lanes/wave, each a float4 -> 64B contiguous
      *(f32x4*)&outP[s*64 + w*16 + quad*4] = (f32x4){pr[0], pr[1], pr[2], pr[3]};
    }
  }
}

// ------------- attention: per (bg, i-row): softmax(q·K*scale + bias) @ V -------------
// bias is [bg][j][i]; staged through LDS with transpose for per-lane j access.
__global__ __launch_bounds__(256) void attn_kernel(
    const float* __restrict__ qb, const float* __restrict__ kb, const float* __restrict__ vb,
    const float* __restrict__ biasb, float* __restrict__ ob){
  __shared__ float qT[64*65], kT[64*65], vT[64*65], bT[64*65];
  int t = threadIdx.x;
  int bg = blockIdx.x>>4, itile = blockIdx.x&15;
  int i0 = itile*64;
  size_t qBase = (size_t)bg*65536;        // == b*C*HW + g*64*HW
  for(int e=t;e<4096;e+=256){
    int d = e>>6, x = e&63;
    qT[d*65 + x] = qb[qBase + (size_t)d*HWPIX + i0 + x];
    kT[d*65 + x] = kb[(size_t)bg*4096 + e];
    vT[d*65 + x] = vb[(size_t)bg*4096 + e];
    bT[x*65 + d] = biasb[(size_t)bg*65536 + (size_t)d*1024 + i0 + x];  // d=j, x=il
  }
  __syncthreads();
  int lane = t&63, w = t>>6;
  for(int rr=0;rr<16;rr++){
    int il = w*16 + rr;
    int i = i0 + il;
    float qreg = qT[lane*65 + il];     // lane l holds q[i][d=l]
    float s0=0.f,s1=0.f,s2=0.f,s3=0.f;
    #pragma unroll 4
    for(int d=0;d<64;d+=4){
      s0 = fmaf(rdlane(qreg,d  ), kT[(d  )*65 + lane], s0);
      s1 = fmaf(rdlane(qreg,d+1), kT[(d+1)*65 + lane], s1);
      s2 = fmaf(rdlane(qreg,d+2), kT[(d+2)*65 + lane], s2);
      s3 = fmaf(rdlane(qreg,d+3), kT[(d+3)*65 + lane], s3);
    }
    float s = (s0+s1)+(s2+s3);
    s = s*SCALE + bT[il*65 + lane];
    float m = s;
    for(int msk=32;msk;msk>>=1) m = fmaxf(m, __shfl_xor(m, msk));
    float p = __expf(s - m);
    float l = p;
    for(int msk=32;msk;msk>>=1) l += __shfl_xor(l, msk);
    p = p / l;
    float o0=0.f,o1=0.f,o2=0.f,o3=0.f;
    #pragma unroll 4
    for(int j=0;j<64;j+=4){
      o0 = fmaf(rdlane(p,j  ), vT[lane*65 + j  ], o0);
      o1 = fmaf(rdlane(p,j+1), vT[lane*65 + j+1], o1);
      o2 = fmaf(rdlane(p,j+2), vT[lane*65 + j+2], o2);
      o3 = fmaf(rdlane(p,j+3), vT[lane*65 + j+3], o3);
    }
    ob[qBase + (size_t)lane*HWPIX + i] = (o0+o1)+(o2+o3);
  }
}

extern "C" void kernel_launch(void* const* d_in, const int* in_sizes, int n_in,
                              void* d_out, int out_size, void* d_ws, size_t ws_size,
                              hipStream_t stream){
  const float* x    = (const float*)d_in[0];
  const float* n1g  = (const float*)d_in[1];
  const float* n1b  = (const float*)d_in[2];
  const float* n2g  = (const float*)d_in[3];
  const float* n2b  = (const float*)d_in[4];
  const float* qw   = (const float*)d_in[5];
  const float* kw   = (const float*)d_in[6];
  const float* vw   = (const float*)d_in[7];
  const float* dww  = (const float*)d_in[8];
  const float* dwb  = (const float*)d_in[9];
  const float* pww  = (const float*)d_in[10];
  const float* cw0  = (const float*)d_in[11];
  const float* cb0  = (const float*)d_in[12];
  const float* cw1  = (const float*)d_in[13];
  const float* cb1  = (const float*)d_in[14];
  const float* cw2  = (const float*)d_in[15];
  const float* cb2  = (const float*)d_in[16];
  const float* ow   = (const float*)d_in[17];
  const float* obb  = (const float*)d_in[18];
  const float* m1w  = (const float*)d_in[19];
  const float* m1b  = (const float*)d_in[20];
  const float* m2w  = (const float*)d_in[21];
  const float* m2b  = (const float*)d_in[22];
  float* out = (float*)d_out;          // reference output dtype is float32
  float* ws = (float*)d_ws;

  // liveness-packed workspace (floats); total 6291456 floats = 25.2 MB
  float* xn      = ws;                 // 1M, live: bn1..sample, then reused by bn2..mlp1
  float* x2      = ws + 1048576;       // 1M, live: outproj..mlp2
  float* q       = ws + 2097152;       // 1M, dead after attn
  float* attnout = ws + 3145728;       // 1M, dead after outproj
  float* biasb   = ws + 4194304;       // 1M, dead after attn  ([bg][j][i] layout)
  float* offg    = ws + 5242880;       // 64K
  float* kv      = ws + 5308416;       // 64K
  float* kbuf    = ws + 5373952;       // 64K
  float* vbuf    = ws + 5439488;       // 64K
  float* vgrid   = ws + 5505024;       // 2K
  float* h       = ws + 2097152;       // 4M, created at mlp1 over dead {q,attnout,biasb,smalls}

  bn_kernel<<<512,256,0,stream>>>(x, n1g, n1b, xn);
  // q = grouped conv1x1 (per-bg 64x64 @ 64x1024), W batch = g = bg&7
  gemm_kernel<<<dim3(16,1,16),256,0,stream>>>(qw, xn, q, nullptr, nullptr,
                                              64,64,1024, 7, 4096, 0);
  dwconv_kernel<<<256,256,0,stream>>>(q, dww, dwb, offg);
  pwgrid_kernel<<<16,64,0,stream>>>(offg, pww, vgrid);
  sample_kernel<<<16,256,0,stream>>>(xn, vgrid, kv);
  gemm_kernel<<<dim3(1,1,16),256,0,stream>>>(kw, kv, kbuf, nullptr, nullptr,
                                             64,64,64, 7, 4096, 0);
  gemm_kernel<<<dim3(1,1,16),256,0,stream>>>(vw, kv, vbuf, nullptr, nullptr,
                                             64,64,64, 7, 4096, 0);
  biasmlp_kernel<<<1024,256,0,stream>>>(cw0, cb0, cw1, cb1, cw2, cb2, vgrid, biasb);
  attn_kernel<<<256,256,0,stream>>>(q, kbuf, vbuf, biasb, attnout);
  // x2 = x + out_w @ attnout + out_b
  gemm_kernel<<<dim3(16,8,2),256,0,stream>>>(ow, attnout, x2, obb, x,
                                             512,512,1024, 0,0,0);
  bn_kernel<<<512,256,0,stream>>>(x2, n2g, n2b, xn);
  // h = gelu(mlp_w1 @ xn + b1)
  gemm_kernel<<<dim3(16,32,2),256,0,stream>>>(m1w, xn, h, m1b, nullptr,
                                              2048,512,1024, 0,0,1);
  // out = x2 + mlp_w2 @ h + b2  (f32 out)
  gemm_kernel<<<dim3(16,8,2),256,0,stream>>>(m2w, h, out, m2b, x2,
                                             512,2048,1024, 0,0,0);
}